// Round 4
// baseline (287.959 us; speedup 1.0000x reference)
//
#include <hip/hip_runtime.h>
#include <stdint.h>

#define T_LEN 512
#define VOCAB 101
#define GSP   136   // bf16 G row pitch in shorts: 32 units*4 gates + 8 pad (272 B, 16B-mult)
#define XPB   516   // token row pitch bytes (512 + 3 replicated tail + pad)
#define HPW   20    // h row pitch in dwords (16 data + 4 pad; 2-way max alias on b128 = free)
#define HB1   (16 * HPW)

typedef short short8 __attribute__((ext_vector_type(8)));
typedef float f32x4  __attribute__((ext_vector_type(4)));

#define LOG2E 1.442695041f
#define L2E2  2.885390082f   // 2*log2(e)

__device__ __forceinline__ float asF(uint32_t u) {
    union { uint32_t i; float f; } x; x.i = u; return x.f;
}
__device__ __forceinline__ float bf2f(uint16_t u) { return asF(((uint32_t)u) << 16); }
__device__ __forceinline__ float bf_lo(uint32_t u) { return asF(u << 16); }
__device__ __forceinline__ float bf_hi(uint32_t u) { return asF(u & 0xFFFF0000u); }
__device__ __forceinline__ uint16_t f2bf(float f) {
    union { float f; uint32_t i; } x; x.f = f;
    return (uint16_t)((x.i + 0x7FFFu + ((x.i >> 16) & 1u)) >> 16);
}
__device__ __forceinline__ float getw(const void* p, int i, bool isbf) {
    return isbf ? bf2f(((const uint16_t*)p)[i]) : ((const float*)p)[i];
}
__device__ __forceinline__ bool detect_bf16(const void* embp) {
    const uint16_t* u = (const uint16_t*)embp;
    int sane = 0;
    for (int i = 0; i < 64; ++i) {
        uint16_t v = u[i];
        int e = (v >> 7) & 0xFF;
        sane += ((e >= 100 && e <= 140) || ((v & 0x7FFFu) == 0)) ? 1 : 0;
    }
    return sane >= 56;
}

// gates for one unit: S = f32x4 preacts (i,f,g,o; i/f/o log2e-scaled, g 2log2e-scaled),
// CST = cell state (2log2e scale). Emits h (f32). 5 exp2 + 2 rcp. Verified r1-r3.
#define GATES(S, CST, HOUT)                                                     \
  {                                                                             \
    float ai = __builtin_amdgcn_exp2f(-(S)[0]);                                 \
    float af = __builtin_amdgcn_exp2f(-(S)[1]);                                 \
    float ag = __builtin_amdgcn_exp2f(-(S)[2]);                                 \
    float ao = __builtin_amdgcn_exp2f(-(S)[3]);                                 \
    float uu = 1.f + ai, ww = 1.f + ag, zz = 1.f + af;                          \
    float uw = uu * ww;                                                         \
    float num = __builtin_fmaf(__builtin_fmaf(ww, -L2E2, 2.f * L2E2), zz,       \
                               (CST) * uw);                                     \
    float cs = num * __builtin_amdgcn_rcpf(zz * uw);                            \
    (CST) = cs;                                                                 \
    float ac = __builtin_amdgcn_exp2f(-cs);                                     \
    float t1 = 1.f + ac;                                                        \
    (HOUT) = (2.f - t1) * __builtin_amdgcn_rcpf((1.f + ao) * t1);               \
  }

// One timestep, phase-pinned. Issue order: bfrag, G(t+1), tok(t+3). In-order lgkm
// retirement makes lgkmcnt(2) an exact bfrag-only wait. G unpack for THIS step's
// C-operand (read last step, drained by last step's lgkmcnt(0)) plus next-address
// arithmetic execute UNDER bfrag's latency. Only the h-write retire precedes the
// barrier; G/tok (issued ~400 cyc earlier) are long retired at lgkmcnt(0).
#define STEP_T(HRoff, HWoff, TOFF, TKUSE, TKDEF)                                    \
  {                                                                                 \
    const uint32_t* hr = &hbuf[HRoff];                                              \
    uint32_t*       hw = &hbuf[HWoff];                                              \
    short8 bfrag = *(const short8*)&hr[n * HPW + 4 * q];                            \
    short8 graw  = *(const short8*)&Gl2[adr1 + (u0i << 2)];                         \
    TKDEF = xr[TOFF];                                                               \
    __builtin_amdgcn_sched_barrier(0);                                              \
    f32x4 gc0, gc1;                                                                 \
    { union { short8 v; uint32_t d[4]; } ug; ug.v = grawP;                          \
      gc0[0] = bf_lo(ug.d[0]); gc0[1] = bf_hi(ug.d[0]);                             \
      gc0[2] = bf_lo(ug.d[1]); gc0[3] = bf_hi(ug.d[1]);                             \
      gc1[0] = bf_lo(ug.d[2]); gc1[1] = bf_hi(ug.d[2]);                             \
      gc1[2] = bf_lo(ug.d[3]); gc1[3] = bf_hi(ug.d[3]); }                           \
    adr1 = (TKUSE) * GSP;                                                           \
    __builtin_amdgcn_sched_barrier(0);                                              \
    asm volatile("s_waitcnt lgkmcnt(2)" ::: "memory");                              \
    __builtin_amdgcn_sched_barrier(0);                                              \
    f32x4 s0 = __builtin_amdgcn_mfma_f32_16x16x32_bf16(afr0, bfrag, gc0, 0, 0, 0);  \
    f32x4 s1 = __builtin_amdgcn_mfma_f32_16x16x32_bf16(afr1, bfrag, gc1, 0, 0, 0);  \
    float h0, h1;                                                                   \
    GATES(s0, c0, h0);                                                              \
    GATES(s1, c1, h1);                                                              \
    uint32_t hp;                                                                    \
    asm("v_cvt_pk_bf16_f32 %0, %1, %2" : "=v"(hp) : "v"(h0), "v"(h1));              \
    hw[n * HPW + 4 * w + q] = hp;                                                   \
    grawP = graw;                                                                   \
    __builtin_amdgcn_sched_barrier(0);                                              \
    asm volatile("s_waitcnt lgkmcnt(0)" ::: "memory");                              \
    __builtin_amdgcn_s_barrier();                                                   \
    __builtin_amdgcn_sched_barrier(0);                                              \
  }

__global__ __launch_bounds__(256, 1) void lstm_fused(
    const int* __restrict__ x, const void* __restrict__ emb,
    const void* __restrict__ Wx, const void* __restrict__ Wh,
    const void* __restrict__ bias, const void* __restrict__ Wfc,
    const void* __restrict__ bfc, void* __restrict__ out)
{
    __shared__ __align__(16) uint16_t Gl2[VOCAB * GSP];     // 27,472 B bf16 preact bias
    __shared__ __align__(16) uint8_t  xt8[16 * XPB];        //  8,256 B packed tokens
    __shared__ __align__(16) uint32_t hbuf[2 * 16 * HPW];   //  2,560 B dbl-buffered h

    const int tid = threadIdx.x;
    const int wl  = tid & 63;
    const int w   = tid >> 6;       // wave 0..3: owns units 8w..8w+7
    const int n   = wl & 15;        // batch row within group
    const int q   = wl >> 4;        // lane owns units 8w+2q, 8w+2q+1
    const int b0  = blockIdx.x * 16;

    const bool isbf = detect_bf16(emb);

    // ---- build G[v][u][g] = bf16( scale(g) * (emb[v]@Wx + b)[32g+u] ) ----
    for (int idx = tid; idx < VOCAB * 128; idx += 256) {
        int v = idx >> 7, cc = idx & 127;
        int u = cc >> 2, g = cc & 3;
        int col = 32 * g + u;
        float acc = getw(bias, col, isbf);
        #pragma unroll 8
        for (int k = 0; k < 32; ++k)
            acc += getw(emb, v * 32 + k, isbf) * getw(Wx, k * 128 + col, isbf);
        Gl2[v * GSP + cc] = f2bf(acc * ((g == 2) ? L2E2 : LOG2E));
    }
    // ---- pack x tokens to u8; replicate first 3 at [512..514] (no wrap mask) ----
    for (int i = tid; i < 2048; i += 256) {
        int row = i >> 7, c4 = i & 127;
        int4 vv = *(const int4*)&x[(b0 + row) * T_LEN + (c4 << 2)];
        uint32_t p = (uint32_t)(vv.x & 255) | ((uint32_t)(vv.y & 255) << 8) |
                     ((uint32_t)(vv.z & 255) << 16) | ((uint32_t)(vv.w & 255) << 24);
        ((uint32_t*)&xt8[row * XPB])[c4] = p;
    }
    for (int i = tid; i < 48; i += 256) {
        int row = i / 3, j = i % 3;
        xt8[row * XPB + 512 + j] = (uint8_t)x[(b0 + row) * T_LEN + j];
    }
    // ---- zero h buffers ----
    for (int i = tid; i < 2 * 16 * HPW; i += 256) hbuf[i] = 0;

    // ---- A fragments: tile jt in {0,1}; D-row m of tile jt <-> (gate m&3,
    //      unit 8w + 2*(m>>2) + jt). A[m=n][k=8q+jj] = sc(n&3)*Wh[8q+jj][col] ----
    short8 afr0, afr1;
    {
        const int gte = n & 3, ul = n >> 2;
        const float sc = (gte == 2) ? L2E2 : LOG2E;
        const int base = 32 * gte + 8 * w + 2 * ul;
        union { short8 v; uint16_t s[8]; } u0, u1;
        #pragma unroll
        for (int jj = 0; jj < 8; ++jj) {
            int kk = 8 * q + jj;
            u0.s[jj] = f2bf(getw(Wh, kk * 128 + base,     isbf) * sc);
            u1.s[jj] = f2bf(getw(Wh, kk * 128 + base + 1, isbf) * sc);
        }
        afr0 = u0.v; afr1 = u1.v;
    }
    __syncthreads();

    const int u0i = 8 * w + 2 * q;      // lane's even unit (tile 0)
    float c0 = 0.f, c1 = 0.f;
    const uint8_t* xr = &xt8[n * XPB];

    // ---- prologue of the 3-deep token/G pipeline ----
    // grawP = G(tok0) raw (unpacked at t=0 under bfrag latency);
    // adr1 = G-row for t+1's read; tkA = tok(2) (t=0 computes adr for t+2).
    short8 grawP;
    int adr1, tkA, tkB;
    {
        int t0 = xr[0], t1 = xr[1];
        tkA = xr[2];
        grawP = *(const short8*)&Gl2[t0 * GSP + (u0i << 2)];
        adr1  = t1 * GSP;
    }

    for (int t = 0; t < T_LEN; t += 2) {
        STEP_T(0,   HB1, t + 3, tkA, tkB);   // even: read buf0, write buf1
        STEP_T(HB1, 0,   t + 4, tkB, tkA);   // odd : read buf1, write buf0
    }

    __syncthreads();   // full drain before epilogue reads

    // ---- epilogue: out = h(T-1) @ W_fc + b_fc ; h(511) lives in buf 0 ----
    if (tid < 32) {
        int row = tid >> 1, cc = tid & 1;
        float acc = getw(bfc, cc, isbf);
        #pragma unroll 8
        for (int k = 0; k < 32; ++k) {
            uint32_t d = hbuf[row * HPW + (k >> 1)];
            float hval = (k & 1) ? bf_hi(d) : bf_lo(d);
            acc += hval * getw(Wfc, k * 2 + cc, isbf);
        }
        int oidx = (b0 + row) * 2 + cc;
        if (isbf) ((uint16_t*)out)[oidx] = f2bf(acc);
        else      ((float*)out)[oidx]    = acc;
    }
}

extern "C" void kernel_launch(void* const* d_in, const int* in_sizes, int n_in,
                              void* d_out, int out_size, void* d_ws, size_t ws_size,
                              hipStream_t stream) {
    (void)in_sizes; (void)n_in; (void)d_ws; (void)ws_size; (void)out_size;
    const int* x = (const int*)d_in[0];
    lstm_fused<<<dim3(256), dim3(256), 0, stream>>>(
        x, d_in[1], d_in[2], d_in[3], d_in[4], d_in[5], d_in[6], d_out);
}

// Round 6
// 245.398 us; speedup vs baseline: 1.1734x; 1.1734x over previous
//
#include <hip/hip_runtime.h>
#include <stdint.h>

#define T_LEN 512
#define VOCAB 101
#define GSP   140   // bf16 G row pitch in shorts (280 B; 280/4=70 dw, gcd(70,32)=2 -> bank spread)
#define XPB   516   // token row pitch bytes (512 + 3 replicated tail + pad)
#define HPW   20    // h row pitch in dwords (16 data + 4 pad; 2-way max alias on b128 = free)
#define HB1   (16 * HPW)

typedef short short8 __attribute__((ext_vector_type(8)));
typedef short s16x4  __attribute__((ext_vector_type(4)));
typedef float f32x4  __attribute__((ext_vector_type(4)));

#define LOG2E 1.442695041f
#define L2E2  2.885390082f   // 2*log2(e)

__device__ __forceinline__ float asF(uint32_t u) {
    union { uint32_t i; float f; } x; x.i = u; return x.f;
}
__device__ __forceinline__ float bf2f(uint16_t u) { return asF(((uint32_t)u) << 16); }
__device__ __forceinline__ float bf_lo(uint32_t u) { return asF(u << 16); }
__device__ __forceinline__ float bf_hi(uint32_t u) { return asF(u & 0xFFFF0000u); }
__device__ __forceinline__ uint16_t f2bf(float f) {
    union { float f; uint32_t i; } x; x.f = f;
    return (uint16_t)((x.i + 0x7FFFu + ((x.i >> 16) & 1u)) >> 16);
}
__device__ __forceinline__ float getw(const void* p, int i, bool isbf) {
    return isbf ? bf2f(((const uint16_t*)p)[i]) : ((const float*)p)[i];
}
__device__ __forceinline__ bool detect_bf16(const void* embp) {
    const uint16_t* u = (const uint16_t*)embp;
    int sane = 0;
    for (int i = 0; i < 64; ++i) {
        uint16_t v = u[i];
        int e = (v >> 7) & 0xFF;
        sane += ((e >= 100 && e <= 140) || ((v & 0x7FFFu) == 0)) ? 1 : 0;
    }
    return sane >= 56;
}

// gates for one unit: S = f32x4 preacts (i,f,g,o; i/f/o log2e-scaled, g 2log2e-scaled),
// CST = cell state (2log2e scale). Emits h (f32). 5 exp2 + 2 rcp. Verified r1-r4.
#define GATES(S, CST, HOUT)                                                     \
  {                                                                             \
    float ai = __builtin_amdgcn_exp2f(-(S)[0]);                                 \
    float af = __builtin_amdgcn_exp2f(-(S)[1]);                                 \
    float ag = __builtin_amdgcn_exp2f(-(S)[2]);                                 \
    float ao = __builtin_amdgcn_exp2f(-(S)[3]);                                 \
    float uu = 1.f + ai, ww = 1.f + ag, zz = 1.f + af;                          \
    float uw = uu * ww;                                                         \
    float num = __builtin_fmaf(__builtin_fmaf(ww, -L2E2, 2.f * L2E2), zz,       \
                               (CST) * uw);                                     \
    float cs = num * __builtin_amdgcn_rcpf(zz * uw);                            \
    (CST) = cs;                                                                 \
    float ac = __builtin_amdgcn_exp2f(-cs);                                     \
    float t1 = 1.f + ac;                                                        \
    (HOUT) = (2.f - t1) * __builtin_amdgcn_rcpf((1.f + ao) * t1);               \
  }

// One timestep. Read issue order HARD-PINNED (bfrag < G < tok) so in-order lgkm
// retirement makes lgkmcnt(2) an exact bfrag-only wait. G unpack for THIS step
// (read last step) + next-address arithmetic execute under bfrag's latency.
#define STEP_T(HRoff, HWoff, TOFF, TKUSE, TKDEF)                                    \
  {                                                                                 \
    const uint32_t* hr = &hbuf[HRoff];                                              \
    uint16_t*       hw = (uint16_t*)&hbuf[HWoff];                                   \
    short8 bfrag = *(const short8*)&hr[n * HPW + 4 * q];                            \
    __builtin_amdgcn_sched_barrier(0);                                              \
    s16x4 graw  = *(const s16x4*)&Gl2[adr1 + (u4 << 2)];                            \
    __builtin_amdgcn_sched_barrier(0);                                              \
    TKDEF = xr[TOFF];                                                               \
    __builtin_amdgcn_sched_barrier(0);                                              \
    f32x4 gc;                                                                       \
    { union { s16x4 v; uint32_t d[2]; } ug; ug.v = grawP;                           \
      gc[0] = bf_lo(ug.d[0]); gc[1] = bf_hi(ug.d[0]);                               \
      gc[2] = bf_lo(ug.d[1]); gc[3] = bf_hi(ug.d[1]); }                             \
    adr1 = (TKUSE) * GSP;                                                           \
    __builtin_amdgcn_sched_barrier(0);                                              \
    asm volatile("s_waitcnt lgkmcnt(2)" ::: "memory");                              \
    __builtin_amdgcn_sched_barrier(0);                                              \
    f32x4 s0 = __builtin_amdgcn_mfma_f32_16x16x32_bf16(afr, bfrag, gc, 0, 0, 0);    \
    float h0;                                                                       \
    GATES(s0, c0, h0);                                                              \
    uint32_t hp;                                                                    \
    asm("v_cvt_pk_bf16_f32 %0, %1, %2" : "=v"(hp) : "v"(h0), "v"(h0));              \
    hw[n * (2 * HPW) + u4] = (uint16_t)hp;                                          \
    grawP = graw;                                                                   \
    __builtin_amdgcn_sched_barrier(0);                                              \
    asm volatile("s_waitcnt lgkmcnt(0)" ::: "memory");                              \
    __builtin_amdgcn_s_barrier();                                                   \
    __builtin_amdgcn_sched_barrier(0);                                              \
  }

__global__ __launch_bounds__(512, 1) void lstm_fused(
    const int* __restrict__ x, const void* __restrict__ emb,
    const void* __restrict__ Wx, const void* __restrict__ Wh,
    const void* __restrict__ bias, const void* __restrict__ Wfc,
    const void* __restrict__ bfc, void* __restrict__ out)
{
    __shared__ __align__(16) uint16_t Gl2[VOCAB * GSP];     // 28,280 B bf16 preact bias
    __shared__ __align__(16) uint8_t  xt8[16 * XPB];        //  8,256 B packed tokens
    __shared__ __align__(16) uint32_t hbuf[2 * 16 * HPW];   //  2,560 B dbl-buffered h

    const int tid = threadIdx.x;
    const int wl  = tid & 63;
    const int w   = tid >> 6;       // wave 0..7: owns units 4w..4w+3
    const int n   = wl & 15;        // batch row within group
    const int q   = wl >> 4;        // lane owns unit 4w+q for row n
    const int u4  = 4 * w + q;      // the lane's unit
    const int b0  = blockIdx.x * 16;

    const bool isbf = detect_bf16(emb);

    // ---- build G[v][u][g] = bf16( scale(g) * (emb[v]@Wx + b)[32g+u] ) ----
    for (int idx = tid; idx < VOCAB * 128; idx += 512) {
        int v = idx >> 7, cc = idx & 127;
        int u = cc >> 2, g = cc & 3;
        int col = 32 * g + u;
        float acc = getw(bias, col, isbf);
        #pragma unroll 8
        for (int k = 0; k < 32; ++k)
            acc += getw(emb, v * 32 + k, isbf) * getw(Wx, k * 128 + col, isbf);
        Gl2[v * GSP + cc] = f2bf(acc * ((g == 2) ? L2E2 : LOG2E));
    }
    // ---- pack x tokens to u8; replicate first 3 at [512..514] (no wrap mask) ----
    for (int i = tid; i < 2048; i += 512) {
        int row = i >> 7, c4 = i & 127;
        int4 vv = *(const int4*)&x[(b0 + row) * T_LEN + (c4 << 2)];
        uint32_t p = (uint32_t)(vv.x & 255) | ((uint32_t)(vv.y & 255) << 8) |
                     ((uint32_t)(vv.z & 255) << 16) | ((uint32_t)(vv.w & 255) << 24);
        ((uint32_t*)&xt8[row * XPB])[c4] = p;
    }
    for (int i = tid; i < 48; i += 512) {
        int row = i / 3, j = i % 3;
        xt8[row * XPB + 512 + j] = (uint8_t)x[(b0 + row) * T_LEN + j];
    }
    // ---- zero h buffers ----
    for (int i = tid; i < 2 * 16 * HPW; i += 512) hbuf[i] = 0;

    // ---- A fragment: single 16x16 tile per wave. D-row m <-> (gate m&3,
    //      unit 4w + (m>>2)); A[m=n][k=8q+jj] = sc(n&3)*Wh[8q+jj][32*(n&3)+4w+(n>>2)].
    //      Lane (n,q) reg j = gate j of unit 4w+q, row n (r2-verified mapping). ----
    short8 afr;
    {
        const int gte = n & 3, ul = n >> 2;
        const float sc = (gte == 2) ? L2E2 : LOG2E;
        const int base = 32 * gte + 4 * w + ul;
        union { short8 v; uint16_t s[8]; } u0;
        #pragma unroll
        for (int jj = 0; jj < 8; ++jj)
            u0.s[jj] = f2bf(getw(Wh, (8 * q + jj) * 128 + base, isbf) * sc);
        afr = u0.v;
    }
    __syncthreads();

    float c0 = 0.f;
    const uint8_t* xr = &xt8[n * XPB];

    // ---- prologue of the 3-deep token/G pipeline ----
    s16x4 grawP;
    int adr1, tkA, tkB;
    {
        int t0 = xr[0], t1 = xr[1];
        tkA = xr[2];
        grawP = *(const s16x4*)&Gl2[t0 * GSP + (u4 << 2)];
        adr1  = t1 * GSP;
    }

    for (int t = 0; t < T_LEN; t += 2) {
        STEP_T(0,   HB1, t + 3, tkA, tkB);   // even: read buf0, write buf1
        STEP_T(HB1, 0,   t + 4, tkB, tkA);   // odd : read buf1, write buf0
    }

    __syncthreads();   // full drain before epilogue reads

    // ---- epilogue: out = h(T-1) @ W_fc + b_fc ; h(511) lives in buf 0 ----
    if (tid < 32) {
        int row = tid >> 1, cc = tid & 1;
        float acc = getw(bfc, cc, isbf);
        #pragma unroll 8
        for (int k = 0; k < 32; ++k) {
            uint32_t d = hbuf[row * HPW + (k >> 1)];
            float hval = (k & 1) ? bf_hi(d) : bf_lo(d);
            acc += hval * getw(Wfc, k * 2 + cc, isbf);
        }
        int oidx = (b0 + row) * 2 + cc;
        if (isbf) ((uint16_t*)out)[oidx] = f2bf(acc);
        else      ((float*)out)[oidx]    = acc;
    }
}

extern "C" void kernel_launch(void* const* d_in, const int* in_sizes, int n_in,
                              void* d_out, int out_size, void* d_ws, size_t ws_size,
                              hipStream_t stream) {
    (void)in_sizes; (void)n_in; (void)d_ws; (void)ws_size; (void)out_size;
    const int* x = (const int*)d_in[0];
    lstm_fused<<<dim3(256), dim3(512), 0, stream>>>(
        x, d_in[1], d_in[2], d_in[3], d_in[4], d_in[5], d_in[6], d_out);
}